// Round 2
// baseline (166.501 us; speedup 1.0000x reference)
//
#include <hip/hip_runtime.h>

// Problem constants (fixed by reference)
#define BATCH   16384
#define NFEAT   512
#define NTREE   64
#define NDEPTH  6
#define NLEAF   64
#define NDOUT   64
#define NLOGIT  384   // NDEPTH * NTREE

typedef float  f32x4  __attribute__((ext_vector_type(4)));
typedef short  short8 __attribute__((ext_vector_type(8)));

union U8 { unsigned short u[8]; short8 v; };
union HP { _Float16 h[4]; ushort4 u; };

// fast fp32 -> bf16, round-half-up (+0x8000): 2 VALU ops, bias negligible
__device__ __forceinline__ unsigned short f2bf(float f) {
    union { float f; unsigned int u; } c; c.f = f;
    return (unsigned short)((c.u + 0x8000u) >> 16);
}

// ---------------------------------------------------------------------------
// prep: blocks 0..63   -> V2[t][d][l] = bf16(leaf[t][l][d] / 64)
//       blocks 64..159 -> Wt[d*64+t][f] = bf16(W[d][f][t])   (384x512 bf16)
// Both via LDS transpose, coalesced in/out. One-time cost ~2 us.
// ---------------------------------------------------------------------------
__global__ __launch_bounds__(256) void prep(const float* __restrict__ leaf,
                                            const float* __restrict__ W,
                                            unsigned short* __restrict__ V2,
                                            unsigned short* __restrict__ Wt) {
    __shared__ float T[64 * 65];
    const int tid = threadIdx.x;
    if (blockIdx.x < 64) {
        const int t = blockIdx.x;
        const float* src = leaf + (size_t)t * 4096;
        for (int j = 0; j < 4; ++j) {
            int idx = tid + 256 * j;            // 0..1023 float4s
            int l = idx >> 4, d4 = idx & 15;
            float4 v = *(const float4*)(src + l * 64 + d4 * 4);
            T[l * 65 + d4 * 4 + 0] = v.x;
            T[l * 65 + d4 * 4 + 1] = v.y;
            T[l * 65 + d4 * 4 + 2] = v.z;
            T[l * 65 + d4 * 4 + 3] = v.w;
        }
        __syncthreads();
        unsigned short* dst = V2 + (size_t)t * 4096;
        for (int j = 0; j < 4; ++j) {
            int idx = tid + 256 * j;
            int d = idx >> 4, l4 = idx & 15;
            ushort4 u;
            u.x = f2bf(T[(l4 * 4 + 0) * 65 + d] * 0.015625f);
            u.y = f2bf(T[(l4 * 4 + 1) * 65 + d] * 0.015625f);
            u.z = f2bf(T[(l4 * 4 + 2) * 65 + d] * 0.015625f);
            u.w = f2bf(T[(l4 * 4 + 3) * 65 + d] * 0.015625f);
            *(ushort4*)(dst + d * 64 + l4 * 4) = u;
        }
    } else {
        const int bid = blockIdx.x - 64;        // 0..95
        const int d = bid >> 4, f0 = (bid & 15) * 32;
        for (int j = 0; j < 2; ++j) {
            int idx = tid + 256 * j;            // 0..511 float4s (32 f x 64 t)
            int f = idx >> 4, c4 = idx & 15;
            float4 v = *(const float4*)(W + ((size_t)d * 512 + f0 + f) * 64 + c4 * 4);
            T[f * 65 + c4 * 4 + 0] = v.x;
            T[f * 65 + c4 * 4 + 1] = v.y;
            T[f * 65 + c4 * 4 + 2] = v.z;
            T[f * 65 + c4 * 4 + 3] = v.w;
        }
        __syncthreads();
        const int t = tid >> 2, c8 = tid & 3;
        U8 u;
        #pragma unroll
        for (int i = 0; i < 8; ++i) u.u[i] = f2bf(T[(c8 * 8 + i) * 65 + t]);
        *(short8*)(Wt + ((size_t)(d * 64 + t)) * 512 + f0 + c8 * 8) = u.v;
    }
}

// ---------------------------------------------------------------------------
// gemm1: SPT[n][b] = fp16( sigmoid( sum_f x[b][f]*W[f][n] + bias[n] ) )
//   n = d*64 + t.  Zero LDS, zero barriers: A and B MFMA fragments are loaded
//   DIRECTLY from global (16B/lane contiguous). Wt (384 KB) is L2-resident;
//   x tile reuse across the wn wave-pair is absorbed by L1.
//   Grid (128 bm, 6 d) = 768 blocks = 3/CU, balanced.
// ---------------------------------------------------------------------------
__global__ __launch_bounds__(256) void gemm1(const float* __restrict__ x,
                                             const unsigned short* __restrict__ Wt,
                                             const float* __restrict__ bias,
                                             _Float16* __restrict__ SPT) {
    const int tid  = threadIdx.x;
    const int wave = tid >> 6, lane = tid & 63;
    const int quad = lane >> 4, l15 = lane & 15;
    const int wm = wave & 1, wn = wave >> 1;
    const int bm = blockIdx.x, d = blockIdx.y;

    const float* xr[4];
    #pragma unroll
    for (int mt = 0; mt < 4; ++mt)
        xr[mt] = x + (size_t)(bm * 128 + wm * 64 + mt * 16 + l15) * NFEAT + quad * 8;
    const unsigned short* wr[2];
    #pragma unroll
    for (int nt = 0; nt < 2; ++nt)
        wr[nt] = Wt + (size_t)(d * 64 + wn * 32 + nt * 16 + l15) * NFEAT + quad * 8;

    f32x4 acc[4][2];
    #pragma unroll
    for (int mt = 0; mt < 4; ++mt)
        #pragma unroll
        for (int nt = 0; nt < 2; ++nt)
            acc[mt][nt] = (f32x4){0.f, 0.f, 0.f, 0.f};

    #pragma unroll 2
    for (int k0 = 0; k0 < NFEAT; k0 += 32) {
        short8 bF[2];
        #pragma unroll
        for (int nt = 0; nt < 2; ++nt)
            bF[nt] = *(const short8*)(wr[nt] + k0);
        short8 aF[4];
        #pragma unroll
        for (int mt = 0; mt < 4; ++mt) {
            float4 a0 = *(const float4*)(xr[mt] + k0);
            float4 a1 = *(const float4*)(xr[mt] + k0 + 4);
            U8 u;
            u.u[0] = f2bf(a0.x); u.u[1] = f2bf(a0.y);
            u.u[2] = f2bf(a0.z); u.u[3] = f2bf(a0.w);
            u.u[4] = f2bf(a1.x); u.u[5] = f2bf(a1.y);
            u.u[6] = f2bf(a1.z); u.u[7] = f2bf(a1.w);
            aF[mt] = u.v;
        }
        #pragma unroll
        for (int mt = 0; mt < 4; ++mt)
            #pragma unroll
            for (int nt = 0; nt < 2; ++nt)
                acc[mt][nt] = __builtin_amdgcn_mfma_f32_16x16x32_bf16(
                    aF[mt], bF[nt], acc[mt][nt], 0, 0, 0);
    }

    // epilogue: bias + sigmoid -> fp16, store transposed SPT[n][b]
    // D layout: col(n)=l15, row(m)=quad*4+reg -> 4 consecutive b per lane (8B store)
    #pragma unroll
    for (int nt = 0; nt < 2; ++nt) {
        int n = d * 64 + wn * 32 + nt * 16 + l15;
        float bv = bias[n];
        #pragma unroll
        for (int mt = 0; mt < 4; ++mt) {
            int row = bm * 128 + wm * 64 + mt * 16 + quad * 4;
            HP h;
            #pragma unroll
            for (int r = 0; r < 4; ++r) {
                float z = acc[mt][nt][r] + bv;
                float p = __builtin_amdgcn_rcpf(1.0f + __expf(-z));
                h.h[r] = (_Float16)p;
            }
            *(ushort4*)((unsigned short*)SPT + (size_t)n * BATCH + row) = h.u;
        }
    }
}

// ---------------------------------------------------------------------------
// tree_all: out[b][d] = sum_t sum_l P[b,t,l] * V2[t][d][l]
// Grid 512 (32-row tiles). Wave w owns trees [16w, 16w+16), all 32 rows.
// No inner barriers, no atomics: B-frags stream from L2-hot V2, P computed
// in-register from fp16 split-probs, cross-wave partials reduced in LDS.
// ---------------------------------------------------------------------------
__global__ __launch_bounds__(256) void tree_all(const _Float16* __restrict__ SPT,
                                                const unsigned short* __restrict__ V2,
                                                float* __restrict__ out) {
    __shared__ _Float16 sp[NLOGIT * 32];    // [n][b_loc]            24 KB
    __shared__ float red[4 * 32 * 66];      // [wave][b_loc][d] pad  33.8 KB
    const int tid  = threadIdx.x;
    const int w = tid >> 6, lane = tid & 63;
    const int quad = lane >> 4, l15 = lane & 15;
    const int r0 = blockIdx.x * 32;

    // stage split-probs: 384 n x 32 b fp16, coalesced 64B-per-n chunks
    for (int j = 0; j < 6; ++j) {
        int c = tid + 256 * j;              // 0..1535 uint4 chunks
        int n = c >> 2, c8 = c & 3;
        *(uint4*)(sp + n * 32 + c8 * 8) =
            *(const uint4*)(SPT + (size_t)n * BATCH + r0 + c8 * 8);
    }
    __syncthreads();

    f32x4 acc[2][4];
    #pragma unroll
    for (int mt = 0; mt < 2; ++mt)
        #pragma unroll
        for (int nt = 0; nt < 4; ++nt)
            acc[mt][nt] = (f32x4){0.f, 0.f, 0.f, 0.f};

    for (int tl = 0; tl < 16; ++tl) {
        const int t = w * 16 + tl;
        // B fragments direct from global (V2 is 512 KB, L2-resident)
        short8 bF[4][2];
        #pragma unroll
        for (int nt = 0; nt < 4; ++nt)
            #pragma unroll
            for (int ks = 0; ks < 2; ++ks)
                bF[nt][ks] = *(const short8*)(V2 + (size_t)t * 4096 +
                                              (nt * 16 + l15) * 64 + ks * 32 + quad * 8);
        // A fragments: path probs. leaf l = ks*32 + quad*8 + j
        short8 aF[2][2];
        #pragma unroll
        for (int mt = 0; mt < 2; ++mt) {
            int rl = mt * 16 + l15;
            float p0 = (float)sp[(0 * 64 + t) * 32 + rl];
            float p1 = (float)sp[(1 * 64 + t) * 32 + rl];
            float p2 = (float)sp[(2 * 64 + t) * 32 + rl];
            float p3 = (float)sp[(3 * 64 + t) * 32 + rl];
            float p4 = (float)sp[(4 * 64 + t) * 32 + rl];
            float p5 = (float)sp[(5 * 64 + t) * 32 + rl];
            float q1 = (quad & 2) ? (1.0f - p1) : p1;
            float q2 = (quad & 1) ? (1.0f - p2) : p2;
            float pre  = q1 * q2;
            float pre0 = p0 * pre;
            float pre1 = (1.0f - p0) * pre;
            float t3a = p3, t3b = 1.0f - p3;
            float t4a = p4, t4b = 1.0f - p4;
            float t5a = p5, t5b = 1.0f - p5;
            float t34[4] = { t3a * t4a, t3a * t4b, t3b * t4a, t3b * t4b };
            U8 a0, a1;
            #pragma unroll
            for (int j = 0; j < 8; ++j) {
                float wj = t34[j >> 1] * ((j & 1) ? t5b : t5a);
                a0.u[j] = f2bf(pre0 * wj);
                a1.u[j] = f2bf(pre1 * wj);
            }
            aF[mt][0] = a0.v;
            aF[mt][1] = a1.v;
        }
        #pragma unroll
        for (int mt = 0; mt < 2; ++mt)
            #pragma unroll
            for (int nt = 0; nt < 4; ++nt)
                #pragma unroll
                for (int ks = 0; ks < 2; ++ks)
                    acc[mt][nt] = __builtin_amdgcn_mfma_f32_16x16x32_bf16(
                        aF[mt][ks], bF[nt][ks], acc[mt][nt], 0, 0, 0);
    }

    // cross-wave reduce in LDS (pad 66 breaks the quad*256-word collision)
    #pragma unroll
    for (int mt = 0; mt < 2; ++mt)
        #pragma unroll
        for (int nt = 0; nt < 4; ++nt)
            #pragma unroll
            for (int r = 0; r < 4; ++r)
                red[w * 2112 + (mt * 16 + quad * 4 + r) * 66 + nt * 16 + l15] =
                    acc[mt][nt][r];
    __syncthreads();
    for (int j = 0; j < 8; ++j) {
        int e = tid + 256 * j;              // 0..2047
        int bl = e >> 6, dd = e & 63;
        float s = red[0 * 2112 + bl * 66 + dd] + red[1 * 2112 + bl * 66 + dd]
                + red[2 * 2112 + bl * 66 + dd] + red[3 * 2112 + bl * 66 + dd];
        out[(size_t)(r0 + bl) * NDOUT + dd] = s;
    }
}

// ---------------------------------------------------------------------------
extern "C" void kernel_launch(void* const* d_in, const int* in_sizes, int n_in,
                              void* d_out, int out_size, void* d_ws, size_t ws_size,
                              hipStream_t stream) {
    const float* x    = (const float*)d_in[0];  // (16384, 512)
    const float* W    = (const float*)d_in[1];  // (6, 512, 64)
    const float* bias = (const float*)d_in[2];  // (6, 64) flat = 384
    const float* leaf = (const float*)d_in[3];  // (64, 64, 64)
    float* out = (float*)d_out;                 // (16384, 64)

    // ws layout: SPT fp16 [384][16384] (12.58 MB) | V2 bf16 (512 KB) | Wt bf16 (384 KB)
    _Float16* SPT = (_Float16*)d_ws;
    unsigned short* V2 = (unsigned short*)((char*)d_ws + (size_t)NLOGIT * BATCH * 2);
    unsigned short* Wt = V2 + (size_t)NTREE * NLEAF * NDOUT;

    prep<<<160, 256, 0, stream>>>(leaf, W, V2, Wt);
    gemm1<<<dim3(BATCH / 128, NDEPTH), 256, 0, stream>>>(x, Wt, bias, SPT);
    tree_all<<<BATCH / 32, 256, 0, stream>>>(SPT, V2, out);
}

// Round 3
// 127.065 us; speedup vs baseline: 1.3104x; 1.3104x over previous
//
#include <hip/hip_runtime.h>

// Problem constants (fixed by reference)
#define BATCH   16384
#define NFEAT   512
#define NTREE   64
#define NDEPTH  6
#define NLEAF   64
#define NDOUT   64
#define NLOGIT  384   // NDEPTH * NTREE

typedef float  f32x4  __attribute__((ext_vector_type(4)));
typedef short  short8 __attribute__((ext_vector_type(8)));

union U8 { unsigned short u[8]; short8 v; };
union HP { _Float16 h[4]; ushort4 u; };

// fast fp32 -> bf16, round-half-up (+0x8000): 2 VALU ops
__device__ __forceinline__ unsigned short f2bf(float f) {
    union { float f; unsigned int u; } c; c.f = f;
    return (unsigned short)((c.u + 0x8000u) >> 16);
}

// async global->LDS DMA, 16B per lane; lds dest must be wave-uniform base,
// HW writes lane i at base + i*16 (m97 pattern).
__device__ __forceinline__ void dma16(const void* g, void* l) {
    __builtin_amdgcn_global_load_lds(
        (const __attribute__((address_space(1))) unsigned int*)g,
        (__attribute__((address_space(3))) unsigned int*)l, 16, 0, 0);
}

// ---------------------------------------------------------------------------
// prep: blocks 0..63   -> V2[t][d][l] = bf16(leaf[t][l][d] / 64)
//       blocks 64..159 -> Wt[n][fblk | (g ^ (n&7))*8 ..] = bf16(W[d][f][t])
//         n = d*64+t; k-groups of 8 XOR-swizzled by n&7 within each 64-block
//         so gemm1's linear DMA + swizzled ds_read is bank-conflict-free.
// ---------------------------------------------------------------------------
__global__ __launch_bounds__(256) void prep(const float* __restrict__ leaf,
                                            const float* __restrict__ W,
                                            unsigned short* __restrict__ V2,
                                            unsigned short* __restrict__ Wt) {
    __shared__ float T[64 * 65];
    const int tid = threadIdx.x;
    if (blockIdx.x < 64) {
        const int t = blockIdx.x;
        const float* src = leaf + (size_t)t * 4096;
        for (int j = 0; j < 4; ++j) {
            int idx = tid + 256 * j;            // 0..1023 float4s
            int l = idx >> 4, d4 = idx & 15;
            float4 v = *(const float4*)(src + l * 64 + d4 * 4);
            T[l * 65 + d4 * 4 + 0] = v.x;
            T[l * 65 + d4 * 4 + 1] = v.y;
            T[l * 65 + d4 * 4 + 2] = v.z;
            T[l * 65 + d4 * 4 + 3] = v.w;
        }
        __syncthreads();
        unsigned short* dst = V2 + (size_t)t * 4096;
        for (int j = 0; j < 4; ++j) {
            int idx = tid + 256 * j;
            int d = idx >> 4, l4 = idx & 15;
            ushort4 u;
            u.x = f2bf(T[(l4 * 4 + 0) * 65 + d] * 0.015625f);
            u.y = f2bf(T[(l4 * 4 + 1) * 65 + d] * 0.015625f);
            u.z = f2bf(T[(l4 * 4 + 2) * 65 + d] * 0.015625f);
            u.w = f2bf(T[(l4 * 4 + 3) * 65 + d] * 0.015625f);
            *(ushort4*)(dst + d * 64 + l4 * 4) = u;
        }
    } else {
        const int bid = blockIdx.x - 64;        // 0..95
        const int d = bid >> 4, f0 = (bid & 15) * 32;
        for (int j = 0; j < 2; ++j) {
            int idx = tid + 256 * j;            // 0..511 float4s (32 f x 64 t)
            int f = idx >> 4, c4 = idx & 15;
            float4 v = *(const float4*)(W + ((size_t)d * 512 + f0 + f) * 64 + c4 * 4);
            T[f * 65 + c4 * 4 + 0] = v.x;
            T[f * 65 + c4 * 4 + 1] = v.y;
            T[f * 65 + c4 * 4 + 2] = v.z;
            T[f * 65 + c4 * 4 + 3] = v.w;
        }
        __syncthreads();
        const int t = tid >> 2, c8 = tid & 3;
        U8 u;
        #pragma unroll
        for (int i = 0; i < 8; ++i) u.u[i] = f2bf(T[(c8 * 8 + i) * 65 + t]);
        // true k-group within this row's 64-block, then XOR-swizzle by n&7
        int g  = ((f0 & 63) >> 3) + c8;         // 0..7
        int gs = g ^ (t & 7);                   // (n&7) == (t&7)
        *(short8*)(Wt + ((size_t)(d * 64 + t)) * 512 + (f0 & ~63) + gs * 8) = u.v;
    }
}

// ---------------------------------------------------------------------------
// gemm1: SPT[n][b] = fp16(sigmoid(sum_f x[b][f]*W[f][n] + bias[n])), n=d*64+t
// m97-style: 128(batch) x 64(n) tile, BK=64, global_load_lds(16B) staging.
// A tile staged fp32 with XOR-swizzled DMA *source* (LDS linear => DMA legal;
// fragment ds_read_b128s land 2-way max on banks = free). B tile from
// pre-swizzled bf16 Wt. Grid (128,6) = 768 blocks = 3/CU.
// ---------------------------------------------------------------------------
__global__ __launch_bounds__(256) void gemm1(const float* __restrict__ x,
                                             const unsigned short* __restrict__ Wt,
                                             const float* __restrict__ bias,
                                             _Float16* __restrict__ SPT) {
    __shared__ float          As[128 * 64];   // [row][16B-chunk swizzled] 32 KB
    __shared__ unsigned short Bs[64 * 64];    // [n][8-elem group swizzled] 8 KB
    const int tid  = threadIdx.x;
    const int wave = tid >> 6, lane = tid & 63;
    const int quad = lane >> 4, l15 = lane & 15;
    const int wm = wave & 1, wn = wave >> 1;  // wave covers 64 rows x 32 n
    const int bm = blockIdx.x, bn = blockIdx.y;   // bn == level d

    const int a_r = lane >> 4, a_c = lane & 15;   // A-DMA: 4 rows x 16 chunks
    const int b_r = lane >> 3, b_c = lane & 7;    // B-DMA: 8 rows x 8 chunks

    f32x4 acc[4][2];
    #pragma unroll
    for (int mt = 0; mt < 4; ++mt)
        #pragma unroll
        for (int nt = 0; nt < 2; ++nt)
            acc[mt][nt] = (f32x4){0.f, 0.f, 0.f, 0.f};

    for (int k0 = 0; k0 < NFEAT; k0 += 64) {
        // ---- A stage: 8 DMA insts/wave, each 1 KB = 4 rows of 256 B
        #pragma unroll
        for (int i = 0; i < 8; ++i) {
            int rl = wave * 32 + i * 4 + a_r;
            const float* g = x + (size_t)(bm * 128 + rl) * NFEAT + k0
                           + ((a_c ^ ((rl & 7) * 2)) * 4);
            dma16(g, (char*)As + (size_t)(wave * 32 + i * 4) * 256);
        }
        // ---- B stage: 2 DMA insts/wave, each 1 KB = 8 rows of 128 B (linear;
        //      swizzle is pre-baked into Wt)
        #pragma unroll
        for (int i = 0; i < 2; ++i) {
            int nl = wave * 16 + i * 8 + b_r;
            const unsigned short* g = Wt + (size_t)(bn * 64 + nl) * NFEAT + k0 + b_c * 8;
            dma16(g, (char*)Bs + (size_t)(wave * 16 + i * 8) * 128);
        }
        __syncthreads();   // compiler emits vmcnt(0) drain before barrier

        short8 bF[2][2];
        #pragma unroll
        for (int nt = 0; nt < 2; ++nt) {
            int n = wn * 32 + nt * 16 + l15;
            #pragma unroll
            for (int ks = 0; ks < 2; ++ks) {
                int c = (ks * 4 + quad) ^ (n & 7);
                bF[nt][ks] = *(const short8*)(Bs + n * 64 + c * 8);
            }
        }
        short8 aF[4][2];
        #pragma unroll
        for (int mt = 0; mt < 4; ++mt) {
            int r = wm * 64 + mt * 16 + l15;
            #pragma unroll
            for (int ks = 0; ks < 2; ++ks) {
                int cb = (ks * 8 + quad * 2) ^ ((r & 7) * 2);
                float4 f0 = *(const float4*)(As + r * 64 + cb * 4);
                float4 f1 = *(const float4*)(As + r * 64 + cb * 4 + 4);
                U8 u;
                u.u[0] = f2bf(f0.x); u.u[1] = f2bf(f0.y);
                u.u[2] = f2bf(f0.z); u.u[3] = f2bf(f0.w);
                u.u[4] = f2bf(f1.x); u.u[5] = f2bf(f1.y);
                u.u[6] = f2bf(f1.z); u.u[7] = f2bf(f1.w);
                aF[mt][ks] = u.v;
            }
        }
        #pragma unroll
        for (int mt = 0; mt < 4; ++mt)
            #pragma unroll
            for (int nt = 0; nt < 2; ++nt)
                #pragma unroll
                for (int ks = 0; ks < 2; ++ks)
                    acc[mt][nt] = __builtin_amdgcn_mfma_f32_16x16x32_bf16(
                        aF[mt][ks], bF[nt][ks], acc[mt][nt], 0, 0, 0);
        __syncthreads();   // protect LDS before next stage
    }

    // ---- epilogue: bias + sigmoid -> fp16, transpose via LDS (reuse As),
    //      then 16B-coalesced stores of SPT[n][b].
    _Float16* Tr = (_Float16*)As;             // [64 n][136 b-pad] 17.4 KB
    #pragma unroll
    for (int nt = 0; nt < 2; ++nt) {
        int nl = wn * 32 + nt * 16 + l15;
        float bv = bias[bn * 64 + nl];
        #pragma unroll
        for (int mt = 0; mt < 4; ++mt) {
            int bl = wm * 64 + mt * 16 + quad * 4;
            HP h;
            #pragma unroll
            for (int r = 0; r < 4; ++r) {
                float z = acc[mt][nt][r] + bv;
                h.h[r] = (_Float16)(1.0f / (1.0f + __expf(-z)));
            }
            *(ushort4*)(Tr + nl * 136 + bl) = h.u;
        }
    }
    __syncthreads();
    #pragma unroll
    for (int j = 0; j < 4; ++j) {
        int c = tid + 256 * j;                // 0..1023: 64 n x 16 chunks
        int n = c >> 4, off = c & 15;
        uint4 v = *(const uint4*)(Tr + n * 136 + off * 8);
        *(uint4*)((unsigned short*)SPT + (size_t)(bn * 64 + n) * BATCH
                  + bm * 128 + off * 8) = v;
    }
}

// ---------------------------------------------------------------------------
// tree_all: out[b][d] = sum_t sum_l P[b,t,l] * V2[t][d][l]
// Grid 512 (32-row tiles), wave w owns trees [16w,16w+16). bF explicitly
// double-buffered (8 b128 global loads in flight over the aF VALU build).
// Cross-wave reduce in fp16 LDS; coalesced 32B final stores. LDS 44.5 KB ->
// 3 blocks/CU = 12 waves/CU.
// ---------------------------------------------------------------------------
__global__ __launch_bounds__(256) void tree_all(const _Float16* __restrict__ SPT,
                                                const unsigned short* __restrict__ V2,
                                                float* __restrict__ out) {
    __shared__ _Float16 sp[NLOGIT * 32];      // [n][b_loc]          24 KB
    __shared__ _Float16 red[4 * 64 * 40];     // [wave][d][b_loc+pad] 20 KB
    const int tid  = threadIdx.x;
    const int w = tid >> 6, lane = tid & 63;
    const int quad = lane >> 4, l15 = lane & 15;
    const int r0 = blockIdx.x * 32;

    // stage split-probs: 384 n-rows x 64 B, 16B chunks
    for (int j = 0; j < 6; ++j) {
        int c = tid + 256 * j;                // 0..1535
        int n = c >> 2, c8 = c & 3;
        *(uint4*)(sp + n * 32 + c8 * 8) =
            *(const uint4*)(SPT + (size_t)n * BATCH + r0 + c8 * 8);
    }
    __syncthreads();

    f32x4 acc[2][4];
    #pragma unroll
    for (int mt = 0; mt < 2; ++mt)
        #pragma unroll
        for (int nt = 0; nt < 4; ++nt)
            acc[mt][nt] = (f32x4){0.f, 0.f, 0.f, 0.f};

    auto loadB = [&](int t, short8 (*bf)[2]) {
        #pragma unroll
        for (int nt = 0; nt < 4; ++nt)
            #pragma unroll
            for (int ks = 0; ks < 2; ++ks)
                bf[nt][ks] = *(const short8*)(V2 + (size_t)t * 4096 +
                                              (nt * 16 + l15) * 64 + ks * 32 + quad * 8);
    };
    auto buildA = [&](int t, short8 (*af)[2]) {
        #pragma unroll
        for (int mt = 0; mt < 2; ++mt) {
            int rl = mt * 16 + l15;
            float p0 = (float)sp[(0 * 64 + t) * 32 + rl];
            float p1 = (float)sp[(1 * 64 + t) * 32 + rl];
            float p2 = (float)sp[(2 * 64 + t) * 32 + rl];
            float p3 = (float)sp[(3 * 64 + t) * 32 + rl];
            float p4 = (float)sp[(4 * 64 + t) * 32 + rl];
            float p5 = (float)sp[(5 * 64 + t) * 32 + rl];
            float q1 = (quad & 2) ? (1.0f - p1) : p1;
            float q2 = (quad & 1) ? (1.0f - p2) : p2;
            float pre  = q1 * q2;
            float pre0 = p0 * pre;
            float pre1 = (1.0f - p0) * pre;
            float t3a = p3, t3b = 1.0f - p3;
            float t4a = p4, t4b = 1.0f - p4;
            float t5a = p5, t5b = 1.0f - p5;
            float t34[4] = { t3a * t4a, t3a * t4b, t3b * t4a, t3b * t4b };
            U8 a0, a1;
            #pragma unroll
            for (int j = 0; j < 8; ++j) {
                float wj = t34[j >> 1] * ((j & 1) ? t5b : t5a);
                a0.u[j] = f2bf(pre0 * wj);
                a1.u[j] = f2bf(pre1 * wj);
            }
            af[mt][0] = a0.v;
            af[mt][1] = a1.v;
        }
    };

    short8 bA[4][2], bB[4][2], aF[2][2];
    loadB(w * 16, bA);
    #pragma unroll 2
    for (int tl = 0; tl < 16; ++tl) {
        const int t = w * 16 + tl;
        short8 (*cur)[2] = (tl & 1) ? bB : bA;
        short8 (*nxt)[2] = (tl & 1) ? bA : bB;
        if (tl + 1 < 16) loadB(t + 1, nxt);   // in flight over aF build
        buildA(t, aF);
        #pragma unroll
        for (int mt = 0; mt < 2; ++mt)
            #pragma unroll
            for (int nt = 0; nt < 4; ++nt)
                #pragma unroll
                for (int ks = 0; ks < 2; ++ks)
                    acc[mt][nt] = __builtin_amdgcn_mfma_f32_16x16x32_bf16(
                        aF[mt][ks], cur[nt][ks], acc[mt][nt], 0, 0, 0);
    }

    // cross-wave reduce: write fp16 partials [w][d][b]
    #pragma unroll
    for (int mt = 0; mt < 2; ++mt)
        #pragma unroll
        for (int nt = 0; nt < 4; ++nt) {
            HP h;
            #pragma unroll
            for (int r = 0; r < 4; ++r) h.h[r] = (_Float16)acc[mt][nt][r];
            *(ushort4*)(red + (w * 64 + nt * 16 + l15) * 40 + mt * 16 + quad * 4) = h.u;
        }
    __syncthreads();
    {
        int b = tid >> 3;                     // 0..31
        int doff = (tid & 7) * 8;             // 0..56
        float s[8];
        #pragma unroll
        for (int i = 0; i < 8; ++i) s[i] = 0.f;
        #pragma unroll
        for (int ww = 0; ww < 4; ++ww)
            #pragma unroll
            for (int i = 0; i < 8; ++i)
                s[i] += (float)red[(ww * 64 + doff + i) * 40 + b];
        float4 o0 = { s[0], s[1], s[2], s[3] };
        float4 o1 = { s[4], s[5], s[6], s[7] };
        float* dst = out + (size_t)(r0 + b) * NDOUT + doff;
        *(float4*)dst = o0;
        *(float4*)(dst + 4) = o1;
    }
}

// ---------------------------------------------------------------------------
extern "C" void kernel_launch(void* const* d_in, const int* in_sizes, int n_in,
                              void* d_out, int out_size, void* d_ws, size_t ws_size,
                              hipStream_t stream) {
    const float* x    = (const float*)d_in[0];  // (16384, 512)
    const float* W    = (const float*)d_in[1];  // (6, 512, 64)
    const float* bias = (const float*)d_in[2];  // (6, 64) flat = 384
    const float* leaf = (const float*)d_in[3];  // (64, 64, 64)
    float* out = (float*)d_out;                 // (16384, 64)

    // ws: SPT fp16 [384][16384] (12.58 MB) | V2 bf16 (512 KB) | Wt bf16 (384 KB)
    _Float16* SPT = (_Float16*)d_ws;
    unsigned short* V2 = (unsigned short*)((char*)d_ws + (size_t)NLOGIT * BATCH * 2);
    unsigned short* Wt = V2 + (size_t)NTREE * NLEAF * NDOUT;

    prep<<<160, 256, 0, stream>>>(leaf, W, V2, Wt);
    gemm1<<<dim3(BATCH / 128, NDEPTH), 256, 0, stream>>>(x, Wt, bias, SPT);
    tree_all<<<BATCH / 32, 256, 0, stream>>>(SPT, V2, out);
}